// Round 1
// baseline (197.875 us; speedup 1.0000x reference)
//
#include <hip/hip_runtime.h>
#include <math.h>

#define N_NODES 50000
#define E_EDGES 800000
#define F_INDIM 128
#define HID 32
#define C_OUT 16

// K1: t1 = x @ W_rel1 ; t2b = x @ W_root1 + b1
// block = 256 = 8 rows x 32 cols; W (2 x 16KB) + x rows (4KB) staged in LDS.
__global__ __launch_bounds__(256) void k1_dense(
        const float* __restrict__ x,
        const float* __restrict__ Wrel, const float* __restrict__ Wroot,
        const float* __restrict__ b1,
        float* __restrict__ t1, float* __restrict__ t2b) {
    __shared__ float sW1[F_INDIM][HID];
    __shared__ float sW2[F_INDIM][HID];
    __shared__ float sx[8][F_INDIM];
    const int tid = threadIdx.x;
    const int rowBase = blockIdx.x * 8;
    for (int i = tid; i < F_INDIM * HID; i += 256) {
        sW1[i >> 5][i & 31] = Wrel[i];
        sW2[i >> 5][i & 31] = Wroot[i];
    }
    for (int i = tid; i < 8 * F_INDIM; i += 256) {
        int rr = rowBase + (i >> 7);
        sx[i >> 7][i & 127] = (rr < N_NODES) ? x[(size_t)rr * F_INDIM + (i & 127)] : 0.f;
    }
    __syncthreads();
    const int r = rowBase + (tid >> 5);
    const int c = tid & 31;
    if (r >= N_NODES) return;
    float acc1 = 0.f, acc2 = 0.f;
    const int lr = tid >> 5;
#pragma unroll 8
    for (int k = 0; k < F_INDIM; ++k) {
        float xv = sx[lr][k];
        acc1 = fmaf(xv, sW1[k][c], acc1);
        acc2 = fmaf(xv, sW2[k][c], acc2);
    }
    t1[(size_t)r * HID + c] = acc1;
    t2b[(size_t)r * HID + c] = acc2 + b1[c];
}

// K2: agg1[dst][c] += ea[e] * t1[src][c]   (thread per edge*32)
__global__ __launch_bounds__(256) void k2_scatter32(
        const int* __restrict__ ei, const float* __restrict__ ea,
        const float* __restrict__ t1, float* __restrict__ agg1) {
    const int idx = blockIdx.x * 256 + threadIdx.x;
    if (idx >= E_EDGES * HID) return;
    const int e = idx >> 5;
    const int c = idx & 31;
    const int s = ei[e];
    const int d = ei[E_EDGES + e];
    const float w = ea[e];
    atomicAdd(&agg1[(size_t)d * HID + c], w * t1[(size_t)s * HID + c]);
}

// K3: h = relu(agg1 + t2b); u1 = h@W_rel2; u2b = h@W_root2 + b2
// block = 256 = 16 rows x 16 cols; h rows staged in LDS.
__global__ __launch_bounds__(256) void k3_layer2(
        const float* __restrict__ agg1, const float* __restrict__ t2b,
        const float* __restrict__ Wrel2, const float* __restrict__ Wroot2,
        const float* __restrict__ b2,
        float* __restrict__ u1, float* __restrict__ u2b) {
    __shared__ float sW1[HID][C_OUT];
    __shared__ float sW2[HID][C_OUT];
    __shared__ float sh[16][HID + 1];
    const int tid = threadIdx.x;
    const int rowBase = blockIdx.x * 16;
    for (int i = tid; i < HID * C_OUT; i += 256) {
        sW1[i >> 4][i & 15] = Wrel2[i];
        sW2[i >> 4][i & 15] = Wroot2[i];
    }
    for (int i = tid; i < 16 * HID; i += 256) {
        int rr = rowBase + (i >> 5);
        int cc = i & 31;
        float v = 0.f;
        if (rr < N_NODES)
            v = agg1[(size_t)rr * HID + cc] + t2b[(size_t)rr * HID + cc];
        sh[i >> 5][cc] = v > 0.f ? v : 0.f;
    }
    __syncthreads();
    const int r = rowBase + (tid >> 4);
    const int c = tid & 15;
    if (r >= N_NODES) return;
    const int lr = tid >> 4;
    float a1 = 0.f, a2 = 0.f;
#pragma unroll
    for (int k = 0; k < HID; ++k) {
        float hv = sh[lr][k];
        a1 = fmaf(hv, sW1[k][c], a1);
        a2 = fmaf(hv, sW2[k][c], a2);
    }
    u1[(size_t)r * C_OUT + c] = a1;
    u2b[(size_t)r * C_OUT + c] = a2 + b2[c];
}

// K4: agg2[dst][c] += ea[e] * u1[src][c]   (thread per edge*16)
__global__ __launch_bounds__(256) void k4_scatter16(
        const int* __restrict__ ei, const float* __restrict__ ea,
        const float* __restrict__ u1, float* __restrict__ agg2) {
    const int idx = blockIdx.x * 256 + threadIdx.x;
    if (idx >= E_EDGES * C_OUT) return;
    const int e = idx >> 4;
    const int c = idx & 15;
    const int s = ei[e];
    const int d = ei[E_EDGES + e];
    const float w = ea[e];
    atomicAdd(&agg2[(size_t)d * C_OUT + c], w * u1[(size_t)s * C_OUT + c]);
}

// K5: out = log_softmax(agg2 + u2b) per row of 16
__global__ __launch_bounds__(256) void k5_lsm(
        const float* __restrict__ agg2, const float* __restrict__ u2b,
        float* __restrict__ out) {
    const int r = blockIdx.x * 256 + threadIdx.x;
    if (r >= N_NODES) return;
    const float4* a4 = (const float4*)(agg2 + (size_t)r * C_OUT);
    const float4* u4 = (const float4*)(u2b + (size_t)r * C_OUT);
    float v[C_OUT];
#pragma unroll
    for (int q = 0; q < 4; ++q) {
        float4 a = a4[q];
        float4 u = u4[q];
        v[q * 4 + 0] = a.x + u.x;
        v[q * 4 + 1] = a.y + u.y;
        v[q * 4 + 2] = a.z + u.z;
        v[q * 4 + 3] = a.w + u.w;
    }
    float mx = v[0];
#pragma unroll
    for (int c = 1; c < C_OUT; ++c) mx = fmaxf(mx, v[c]);
    float s = 0.f;
#pragma unroll
    for (int c = 0; c < C_OUT; ++c) s += expf(v[c] - mx);
    const float lse = mx + logf(s);
    float4* o4 = (float4*)(out + (size_t)r * C_OUT);
#pragma unroll
    for (int q = 0; q < 4; ++q) {
        float4 o;
        o.x = v[q * 4 + 0] - lse;
        o.y = v[q * 4 + 1] - lse;
        o.z = v[q * 4 + 2] - lse;
        o.w = v[q * 4 + 3] - lse;
        o4[q] = o;
    }
}

extern "C" void kernel_launch(void* const* d_in, const int* in_sizes, int n_in,
                              void* d_out, int out_size, void* d_ws, size_t ws_size,
                              hipStream_t stream) {
    const float* x      = (const float*)d_in[0];
    const int*   ei     = (const int*)d_in[1];
    const float* ea     = (const float*)d_in[2];
    const float* Wrel1  = (const float*)d_in[3];
    const float* Wroot1 = (const float*)d_in[4];
    const float* b1     = (const float*)d_in[5];
    const float* Wrel2  = (const float*)d_in[6];
    const float* Wroot2 = (const float*)d_in[7];
    const float* b2     = (const float*)d_in[8];
    float* out = (float*)d_out;

    float* ws   = (float*)d_ws;
    float* t1   = ws;                       // N*32
    float* t2b  = ws + (size_t)N_NODES * 32;  // N*32
    float* agg1 = ws + (size_t)N_NODES * 64;  // N*32
    float* u1   = ws + (size_t)N_NODES * 96;  // N*16
    float* u2b  = ws + (size_t)N_NODES * 112; // N*16
    float* agg2 = ws + (size_t)N_NODES * 128; // N*16
    // total: N*144 floats = 28.8 MB

    hipMemsetAsync(agg1, 0, (size_t)N_NODES * 32 * sizeof(float), stream);
    hipMemsetAsync(agg2, 0, (size_t)N_NODES * 16 * sizeof(float), stream);

    k1_dense<<<(N_NODES + 7) / 8, 256, 0, stream>>>(x, Wrel1, Wroot1, b1, t1, t2b);
    k2_scatter32<<<(E_EDGES * HID) / 256, 256, 0, stream>>>(ei, ea, t1, agg1);
    k3_layer2<<<(N_NODES + 15) / 16, 256, 0, stream>>>(agg1, t2b, Wrel2, Wroot2, b2, u1, u2b);
    k4_scatter16<<<(E_EDGES * C_OUT) / 256, 256, 0, stream>>>(ei, ea, u1, agg2);
    k5_lsm<<<(N_NODES + 255) / 256, 256, 0, stream>>>(agg2, u2b, out);
}